// Round 11
// baseline (93.050 us; speedup 1.0000x reference)
//
#include <hip/hip_runtime.h>
#include <math.h>

#define FDIM 256
#define EPSF 1e-16f
#define K4_ROWS 2

typedef float f32x4 __attribute__((ext_vector_type(4)));

__device__ __forceinline__ float dot4v(f32x4 a, f32x4 b) {
    return a.x * b.x + a.y * b.y + a.z * b.z + a.w * b.w;
}

// Non-temporal 16B load: stream x without allocating cache lines.
// Proven +3.8us in R7 (49.8 vs 53.6, same structure without NT).
__device__ __forceinline__ f32x4 ntload(const float* p) {
    return __builtin_nontemporal_load(reinterpret_cast<const f32x4*>(p));
}

// Prologue: seg_start[g] = first row index with batch[row] >= g, g in [0,G].
__global__ void __launch_bounds__(256) k_ranges(const int* __restrict__ batch,
                                                int* __restrict__ seg_start,
                                                int N, int G) {
    int i = blockIdx.x * blockDim.x + threadIdx.x;
    if (i > N) return;
    int b  = (i == N) ? G : batch[i];
    int bp = (i == 0) ? -1 : batch[i - 1];
    for (int g = bp + 1; g <= b; ++g) seg_start[g] = i;
}

// Fused pass (R7 structure; ONLY change: __launch_bounds__(256,8) to pin
// 8 waves/SIMD = 8 blocks/CU — R7's ~80 VGPR allowed only 6).
// gate + exp + weighted partial sum, single read of x. 2 blocks per segment;
// block = 4 waves; wave = 4 groups of 16 lanes; each group owns one row per
// iteration; unroll x2. 4-step xor-reduce within the 16-lane group; one exp
// serves 4 rows/wave. exp without max-subtract is safe (gate ~ N(0,1)).
__global__ void __launch_bounds__(256, 8) k_fused(const int* __restrict__ seg_start,
                                                  const float* __restrict__ x,
                                                  const float* __restrict__ Wg,
                                                  float* __restrict__ yp,
                                                  float* __restrict__ sp) {
    int b = blockIdx.x;
    int g = b >> 1, half = b & 1;
    int s0 = seg_start[g];
    int e0 = seg_start[g + 1];
    int mid = s0 + ((e0 - s0) >> 1);
    int rs = half ? mid : s0;
    int re = half ? e0 : mid;

    __shared__ float s_s[16];
    __shared__ float s_acc[16][FDIM];

    int wave = threadIdx.x >> 6;
    int group = (threadIdx.x >> 4) & 3;
    int l16 = threadIdx.x & 15;
    int part = (wave << 2) | group;

    const f32x4 wg0 = *reinterpret_cast<const f32x4*>(Wg +   0 + l16 * 4);
    const f32x4 wg1 = *reinterpret_cast<const f32x4*>(Wg +  64 + l16 * 4);
    const f32x4 wg2 = *reinterpret_cast<const f32x4*>(Wg + 128 + l16 * 4);
    const f32x4 wg3 = *reinterpret_cast<const f32x4*>(Wg + 192 + l16 * 4);

    f32x4 a0 = (f32x4)0.f, a1 = (f32x4)0.f, a2 = (f32x4)0.f, a3 = (f32x4)0.f;
    float s = 0.f;

    int r = rs + part;
    for (; r + 16 < re; r += 32) {
        const float* rp0 = x + (size_t)r * FDIM;
        const float* rp1 = x + (size_t)(r + 16) * FDIM;
        f32x4 x0 = ntload(rp0 +   0 + l16 * 4);
        f32x4 x1 = ntload(rp0 +  64 + l16 * 4);
        f32x4 x2 = ntload(rp0 + 128 + l16 * 4);
        f32x4 x3 = ntload(rp0 + 192 + l16 * 4);
        f32x4 y0 = ntload(rp1 +   0 + l16 * 4);
        f32x4 y1 = ntload(rp1 +  64 + l16 * 4);
        f32x4 y2 = ntload(rp1 + 128 + l16 * 4);
        f32x4 y3 = ntload(rp1 + 192 + l16 * 4);
        float d0 = dot4v(x0, wg0) + dot4v(x1, wg1) + dot4v(x2, wg2) + dot4v(x3, wg3);
        float d1 = dot4v(y0, wg0) + dot4v(y1, wg1) + dot4v(y2, wg2) + dot4v(y3, wg3);
        #pragma unroll
        for (int off = 1; off < 16; off <<= 1) {
            d0 += __shfl_xor(d0, off, 64);
            d1 += __shfl_xor(d1, off, 64);
        }
        float w0 = __expf(d0);
        float w1 = __expf(d1);
        a0 += w0 * x0; a1 += w0 * x1; a2 += w0 * x2; a3 += w0 * x3;
        a0 += w1 * y0; a1 += w1 * y1; a2 += w1 * y2; a3 += w1 * y3;
        s += w0 + w1;
    }
    if (r < re) {
        const float* rp = x + (size_t)r * FDIM;
        f32x4 x0 = ntload(rp +   0 + l16 * 4);
        f32x4 x1 = ntload(rp +  64 + l16 * 4);
        f32x4 x2 = ntload(rp + 128 + l16 * 4);
        f32x4 x3 = ntload(rp + 192 + l16 * 4);
        float d = dot4v(x0, wg0) + dot4v(x1, wg1) + dot4v(x2, wg2) + dot4v(x3, wg3);
        #pragma unroll
        for (int off = 1; off < 16; off <<= 1) d += __shfl_xor(d, off, 64);
        float w = __expf(d);
        a0 += w * x0; a1 += w * x1; a2 += w * x2; a3 += w * x3;
        s += w;
    }

    *reinterpret_cast<f32x4*>(&s_acc[part][  0 + l16 * 4]) = a0;
    *reinterpret_cast<f32x4*>(&s_acc[part][ 64 + l16 * 4]) = a1;
    *reinterpret_cast<f32x4*>(&s_acc[part][128 + l16 * 4]) = a2;
    *reinterpret_cast<f32x4*>(&s_acc[part][192 + l16 * 4]) = a3;
    if (l16 == 0) s_s[part] = s;
    __syncthreads();

    int c = threadIdx.x;
    float v = 0.f;
    #pragma unroll
    for (int p = 0; p < 16; ++p) v += s_acc[p][c];
    yp[(size_t)b * FDIM + c] = v;
    if (threadIdx.x == 0) {
        float t = 0.f;
        #pragma unroll
        for (int p = 0; p < 16; ++p) t += s_s[p];
        sp[b] = t;
    }
}

// k4 (R7's exact version — best of 4 variants tried): merge the 2 partials
// per segment, normalize, out = ynorm @ Wn + sum_alpha (x) bn.
// 2 segments per 256-thread block -> 512 blocks (2/CU overlap each other).
__global__ void __launch_bounds__(256) k4_out(const float* __restrict__ yp,
                                              const float* __restrict__ sp,
                                              const float* __restrict__ Wn,
                                              const float* __restrict__ bn,
                                              float* __restrict__ out, int G) {
    int g0 = blockIdx.x * K4_ROWS;
    __shared__ float ys[K4_ROWS][FDIM];
    __shared__ float s_alpha[K4_ROWS];
    int c = threadIdx.x;
    #pragma unroll
    for (int r = 0; r < K4_ROWS; ++r) {
        int g = g0 + r;
        if (g < G) {
            float sg = sp[2 * g] + sp[2 * g + 1];
            float inv = 1.0f / (sg + EPSF);
            ys[r][c] = (yp[(size_t)(2 * g) * FDIM + c] +
                        yp[(size_t)(2 * g + 1) * FDIM + c]) * inv;
            if (c == 0) s_alpha[r] = sg * inv;
        } else {
            ys[r][c] = 0.f;
            if (c == 0) s_alpha[r] = 0.f;
        }
    }
    __syncthreads();
    float acc[K4_ROWS];
    #pragma unroll
    for (int r = 0; r < K4_ROWS; ++r) acc[r] = 0.f;
    #pragma unroll 8
    for (int k = 0; k < FDIM; ++k) {
        float w = Wn[k * FDIM + c];
        #pragma unroll
        for (int r = 0; r < K4_ROWS; ++r) acc[r] += ys[r][k] * w;
    }
    float bv = bn[c];
    #pragma unroll
    for (int r = 0; r < K4_ROWS; ++r) {
        int g = g0 + r;
        if (g < G) out[(size_t)g * FDIM + c] = acc[r] + s_alpha[r] * bv;
    }
}

extern "C" void kernel_launch(void* const* d_in, const int* in_sizes, int n_in,
                              void* d_out, int out_size, void* d_ws, size_t ws_size,
                              hipStream_t stream) {
    const float* x     = (const float*)d_in[0];
    const int*   batch = (const int*)d_in[1];
    const float* Wg    = (const float*)d_in[3];
    const float* Wn    = (const float*)d_in[5];
    const float* bn    = (const float*)d_in[6];
    float* out = (float*)d_out;

    int N = in_sizes[1];
    int G = out_size / FDIM;

    int*   seg_start = (int*)d_ws;                     // G+1 ints
    float* sp = (float*)(seg_start + ((G + 2) & ~1));  // 2G floats
    float* yp = sp + 2 * G;                            // 2G * FDIM floats

    k_ranges<<<(N + 1 + 255) / 256, 256, 0, stream>>>(batch, seg_start, N, G);
    k_fused<<<2 * G, 256, 0, stream>>>(seg_start, x, Wg, yp, sp);
    k4_out<<<(G + K4_ROWS - 1) / K4_ROWS, 256, 0, stream>>>(yp, sp, Wn, bn, out, G);
}

// Round 12
// 59.507 us; speedup vs baseline: 1.5637x; 1.5637x over previous
//
#include <hip/hip_runtime.h>
#include <math.h>

#define FDIM 256
#define EPSF 1e-16f
#define K4_ROWS 2

typedef float f32x4 __attribute__((ext_vector_type(4)));

__device__ __forceinline__ float dot4v(f32x4 a, f32x4 b) {
    return a.x * b.x + a.y * b.y + a.z * b.z + a.w * b.w;
}

// Non-temporal 16B load: stream x without allocating cache lines.
// Proven +3.8us in R7 (49.8 vs 53.6, same structure without NT).
__device__ __forceinline__ f32x4 ntload(const float* p) {
    return __builtin_nontemporal_load(reinterpret_cast<const f32x4*>(p));
}

// Prologue: seg_start[g] = first row index with batch[row] >= g, g in [0,G].
__global__ void __launch_bounds__(256) k_ranges(const int* __restrict__ batch,
                                                int* __restrict__ seg_start,
                                                int N, int G) {
    int i = blockIdx.x * blockDim.x + threadIdx.x;
    if (i > N) return;
    int b  = (i == N) ? G : batch[i];
    int bp = (i == 0) ? -1 : batch[i - 1];
    for (int g = bp + 1; g <= b; ++g) seg_start[g] = i;
}

// Fused pass (R7 structure, byte-identical — natural VGPR allocation, ~6
// blocks/CU; forcing 8 (R11) spilled and cost 2x). gate + exp + weighted
// partial sum, single read of x. 2 blocks per segment; block = 4 waves;
// wave = 4 groups of 16 lanes; each group owns one row per iteration;
// unroll x2. 4-step xor-reduce within the 16-lane group; one exp serves
// 4 rows/wave. exp without max-subtract is safe (gate ~ N(0,1)).
__global__ void __launch_bounds__(256) k_fused(const int* __restrict__ seg_start,
                                               const float* __restrict__ x,
                                               const float* __restrict__ Wg,
                                               float* __restrict__ yp,
                                               float* __restrict__ sp) {
    int b = blockIdx.x;
    int g = b >> 1, half = b & 1;
    int s0 = seg_start[g];
    int e0 = seg_start[g + 1];
    int mid = s0 + ((e0 - s0) >> 1);
    int rs = half ? mid : s0;
    int re = half ? e0 : mid;

    __shared__ float s_s[16];
    __shared__ float s_acc[16][FDIM];

    int wave = threadIdx.x >> 6;
    int group = (threadIdx.x >> 4) & 3;
    int l16 = threadIdx.x & 15;
    int part = (wave << 2) | group;

    const f32x4 wg0 = *reinterpret_cast<const f32x4*>(Wg +   0 + l16 * 4);
    const f32x4 wg1 = *reinterpret_cast<const f32x4*>(Wg +  64 + l16 * 4);
    const f32x4 wg2 = *reinterpret_cast<const f32x4*>(Wg + 128 + l16 * 4);
    const f32x4 wg3 = *reinterpret_cast<const f32x4*>(Wg + 192 + l16 * 4);

    f32x4 a0 = (f32x4)0.f, a1 = (f32x4)0.f, a2 = (f32x4)0.f, a3 = (f32x4)0.f;
    float s = 0.f;

    int r = rs + part;
    for (; r + 16 < re; r += 32) {
        const float* rp0 = x + (size_t)r * FDIM;
        const float* rp1 = x + (size_t)(r + 16) * FDIM;
        f32x4 x0 = ntload(rp0 +   0 + l16 * 4);
        f32x4 x1 = ntload(rp0 +  64 + l16 * 4);
        f32x4 x2 = ntload(rp0 + 128 + l16 * 4);
        f32x4 x3 = ntload(rp0 + 192 + l16 * 4);
        f32x4 y0 = ntload(rp1 +   0 + l16 * 4);
        f32x4 y1 = ntload(rp1 +  64 + l16 * 4);
        f32x4 y2 = ntload(rp1 + 128 + l16 * 4);
        f32x4 y3 = ntload(rp1 + 192 + l16 * 4);
        float d0 = dot4v(x0, wg0) + dot4v(x1, wg1) + dot4v(x2, wg2) + dot4v(x3, wg3);
        float d1 = dot4v(y0, wg0) + dot4v(y1, wg1) + dot4v(y2, wg2) + dot4v(y3, wg3);
        #pragma unroll
        for (int off = 1; off < 16; off <<= 1) {
            d0 += __shfl_xor(d0, off, 64);
            d1 += __shfl_xor(d1, off, 64);
        }
        float w0 = __expf(d0);
        float w1 = __expf(d1);
        a0 += w0 * x0; a1 += w0 * x1; a2 += w0 * x2; a3 += w0 * x3;
        a0 += w1 * y0; a1 += w1 * y1; a2 += w1 * y2; a3 += w1 * y3;
        s += w0 + w1;
    }
    if (r < re) {
        const float* rp = x + (size_t)r * FDIM;
        f32x4 x0 = ntload(rp +   0 + l16 * 4);
        f32x4 x1 = ntload(rp +  64 + l16 * 4);
        f32x4 x2 = ntload(rp + 128 + l16 * 4);
        f32x4 x3 = ntload(rp + 192 + l16 * 4);
        float d = dot4v(x0, wg0) + dot4v(x1, wg1) + dot4v(x2, wg2) + dot4v(x3, wg3);
        #pragma unroll
        for (int off = 1; off < 16; off <<= 1) d += __shfl_xor(d, off, 64);
        float w = __expf(d);
        a0 += w * x0; a1 += w * x1; a2 += w * x2; a3 += w * x3;
        s += w;
    }

    *reinterpret_cast<f32x4*>(&s_acc[part][  0 + l16 * 4]) = a0;
    *reinterpret_cast<f32x4*>(&s_acc[part][ 64 + l16 * 4]) = a1;
    *reinterpret_cast<f32x4*>(&s_acc[part][128 + l16 * 4]) = a2;
    *reinterpret_cast<f32x4*>(&s_acc[part][192 + l16 * 4]) = a3;
    if (l16 == 0) s_s[part] = s;
    __syncthreads();

    int c = threadIdx.x;
    float v = 0.f;
    #pragma unroll
    for (int p = 0; p < 16; ++p) v += s_acc[p][c];
    yp[(size_t)b * FDIM + c] = v;
    if (threadIdx.x == 0) {
        float t = 0.f;
        #pragma unroll
        for (int p = 0; p < 16; ++p) t += s_s[p];
        sp[b] = t;
    }
}

// k4 (CHANGED: explicit k-tiling into registers): merge the 2 partials per
// segment, normalize, out = ynorm @ Wn + sum_alpha (x) bn.
// 2 segments per 256-thread block -> 512 blocks (2/CU).
// Per 8-k tile: 4 x ds_read_b128 pull ys[0/1][k..k+8) into registers, then
// 8 coalesced Wn loads + 16 FMA — 4x fewer LDS instructions than the
// per-k broadcast version (which was ds_read-issue-bound).
__global__ void __launch_bounds__(256) k4_out(const float* __restrict__ yp,
                                              const float* __restrict__ sp,
                                              const float* __restrict__ Wn,
                                              const float* __restrict__ bn,
                                              float* __restrict__ out, int G) {
    int g0 = blockIdx.x * K4_ROWS;
    __shared__ float ys[K4_ROWS][FDIM];
    __shared__ float s_alpha[K4_ROWS];
    int c = threadIdx.x;
    #pragma unroll
    for (int r = 0; r < K4_ROWS; ++r) {
        int g = g0 + r;
        if (g < G) {
            float sg = sp[2 * g] + sp[2 * g + 1];
            float inv = 1.0f / (sg + EPSF);
            ys[r][c] = (yp[(size_t)(2 * g) * FDIM + c] +
                        yp[(size_t)(2 * g + 1) * FDIM + c]) * inv;
            if (c == 0) s_alpha[r] = sg * inv;
        } else {
            ys[r][c] = 0.f;
            if (c == 0) s_alpha[r] = 0.f;
        }
    }
    __syncthreads();

    float acc0 = 0.f, acc1 = 0.f;
    for (int k0 = 0; k0 < FDIM; k0 += 8) {
        f32x4 ya0 = *reinterpret_cast<const f32x4*>(&ys[0][k0]);
        f32x4 ya1 = *reinterpret_cast<const f32x4*>(&ys[0][k0 + 4]);
        f32x4 yb0 = *reinterpret_cast<const f32x4*>(&ys[1][k0]);
        f32x4 yb1 = *reinterpret_cast<const f32x4*>(&ys[1][k0 + 4]);
        #pragma unroll
        for (int j = 0; j < 4; ++j) {
            float w = Wn[(k0 + j) * FDIM + c];
            acc0 = fmaf(ya0[j], w, acc0);
            acc1 = fmaf(yb0[j], w, acc1);
        }
        #pragma unroll
        for (int j = 0; j < 4; ++j) {
            float w = Wn[(k0 + 4 + j) * FDIM + c];
            acc0 = fmaf(ya1[j], w, acc0);
            acc1 = fmaf(yb1[j], w, acc1);
        }
    }

    float bv = bn[c];
    if (g0 < G)     out[(size_t)g0 * FDIM + c]       = acc0 + s_alpha[0] * bv;
    if (g0 + 1 < G) out[(size_t)(g0 + 1) * FDIM + c] = acc1 + s_alpha[1] * bv;
}

extern "C" void kernel_launch(void* const* d_in, const int* in_sizes, int n_in,
                              void* d_out, int out_size, void* d_ws, size_t ws_size,
                              hipStream_t stream) {
    const float* x     = (const float*)d_in[0];
    const int*   batch = (const int*)d_in[1];
    const float* Wg    = (const float*)d_in[3];
    const float* Wn    = (const float*)d_in[5];
    const float* bn    = (const float*)d_in[6];
    float* out = (float*)d_out;

    int N = in_sizes[1];
    int G = out_size / FDIM;

    int*   seg_start = (int*)d_ws;                     // G+1 ints
    float* sp = (float*)(seg_start + ((G + 2) & ~1));  // 2G floats
    float* yp = sp + 2 * G;                            // 2G * FDIM floats

    k_ranges<<<(N + 1 + 255) / 256, 256, 0, stream>>>(batch, seg_start, N, G);
    k_fused<<<2 * G, 256, 0, stream>>>(seg_start, x, Wg, yp, sp);
    k4_out<<<(G + K4_ROWS - 1) / K4_ROWS, 256, 0, stream>>>(yp, sp, Wn, bn, out, G);
}

// Round 13
// 48.738 us; speedup vs baseline: 1.9092x; 1.2210x over previous
//
#include <hip/hip_runtime.h>
#include <math.h>

#define FDIM 256
#define EPSF 1e-16f
#define K4_ROWS 2

typedef float f32x4 __attribute__((ext_vector_type(4)));

__device__ __forceinline__ float dot4v(f32x4 a, f32x4 b) {
    return a.x * b.x + a.y * b.y + a.z * b.z + a.w * b.w;
}

// Non-temporal 16B load: stream x without allocating cache lines.
// Proven +3.8us in R7 (49.8 vs 53.6, same structure without NT).
__device__ __forceinline__ f32x4 ntload(const float* p) {
    return __builtin_nontemporal_load(reinterpret_cast<const f32x4*>(p));
}

// Prologue: seg_start[g] = first row index with batch[row] >= g, g in [0,G].
__global__ void __launch_bounds__(256) k_ranges(const int* __restrict__ batch,
                                                int* __restrict__ seg_start,
                                                int N, int G) {
    int i = blockIdx.x * blockDim.x + threadIdx.x;
    if (i > N) return;
    int b  = (i == N) ? G : batch[i];
    int bp = (i == 0) ? -1 : batch[i - 1];
    for (int g = bp + 1; g <= b; ++g) seg_start[g] = i;
}

// Fused pass (R7 byte-exact): gate + exp + weighted partial sum, single read
// of x. 2 blocks per segment; block = 4 waves; wave = 4 groups of 16 lanes;
// each group owns one row per iteration; unroll x2. 4-step xor-reduce within
// the 16-lane group; one exp serves 4 rows/wave. exp without max-subtract is
// safe (gate ~ N(0,1)); bg cancels in softmax.
__global__ void __launch_bounds__(256) k_fused(const int* __restrict__ seg_start,
                                               const float* __restrict__ x,
                                               const float* __restrict__ Wg,
                                               float* __restrict__ yp,
                                               float* __restrict__ sp) {
    int b = blockIdx.x;
    int g = b >> 1, half = b & 1;
    int s0 = seg_start[g];
    int e0 = seg_start[g + 1];
    int mid = s0 + ((e0 - s0) >> 1);
    int rs = half ? mid : s0;
    int re = half ? e0 : mid;

    __shared__ float s_s[16];
    __shared__ float s_acc[16][FDIM];

    int wave = threadIdx.x >> 6;
    int group = (threadIdx.x >> 4) & 3;
    int l16 = threadIdx.x & 15;
    int part = (wave << 2) | group;

    const f32x4 wg0 = *reinterpret_cast<const f32x4*>(Wg +   0 + l16 * 4);
    const f32x4 wg1 = *reinterpret_cast<const f32x4*>(Wg +  64 + l16 * 4);
    const f32x4 wg2 = *reinterpret_cast<const f32x4*>(Wg + 128 + l16 * 4);
    const f32x4 wg3 = *reinterpret_cast<const f32x4*>(Wg + 192 + l16 * 4);

    f32x4 a0 = (f32x4)0.f, a1 = (f32x4)0.f, a2 = (f32x4)0.f, a3 = (f32x4)0.f;
    float s = 0.f;

    int r = rs + part;
    for (; r + 16 < re; r += 32) {
        const float* rp0 = x + (size_t)r * FDIM;
        const float* rp1 = x + (size_t)(r + 16) * FDIM;
        f32x4 x0 = ntload(rp0 +   0 + l16 * 4);
        f32x4 x1 = ntload(rp0 +  64 + l16 * 4);
        f32x4 x2 = ntload(rp0 + 128 + l16 * 4);
        f32x4 x3 = ntload(rp0 + 192 + l16 * 4);
        f32x4 y0 = ntload(rp1 +   0 + l16 * 4);
        f32x4 y1 = ntload(rp1 +  64 + l16 * 4);
        f32x4 y2 = ntload(rp1 + 128 + l16 * 4);
        f32x4 y3 = ntload(rp1 + 192 + l16 * 4);
        float d0 = dot4v(x0, wg0) + dot4v(x1, wg1) + dot4v(x2, wg2) + dot4v(x3, wg3);
        float d1 = dot4v(y0, wg0) + dot4v(y1, wg1) + dot4v(y2, wg2) + dot4v(y3, wg3);
        #pragma unroll
        for (int off = 1; off < 16; off <<= 1) {
            d0 += __shfl_xor(d0, off, 64);
            d1 += __shfl_xor(d1, off, 64);
        }
        float w0 = __expf(d0);
        float w1 = __expf(d1);
        a0 += w0 * x0; a1 += w0 * x1; a2 += w0 * x2; a3 += w0 * x3;
        a0 += w1 * y0; a1 += w1 * y1; a2 += w1 * y2; a3 += w1 * y3;
        s += w0 + w1;
    }
    if (r < re) {
        const float* rp = x + (size_t)r * FDIM;
        f32x4 x0 = ntload(rp +   0 + l16 * 4);
        f32x4 x1 = ntload(rp +  64 + l16 * 4);
        f32x4 x2 = ntload(rp + 128 + l16 * 4);
        f32x4 x3 = ntload(rp + 192 + l16 * 4);
        float d = dot4v(x0, wg0) + dot4v(x1, wg1) + dot4v(x2, wg2) + dot4v(x3, wg3);
        #pragma unroll
        for (int off = 1; off < 16; off <<= 1) d += __shfl_xor(d, off, 64);
        float w = __expf(d);
        a0 += w * x0; a1 += w * x1; a2 += w * x2; a3 += w * x3;
        s += w;
    }

    *reinterpret_cast<f32x4*>(&s_acc[part][  0 + l16 * 4]) = a0;
    *reinterpret_cast<f32x4*>(&s_acc[part][ 64 + l16 * 4]) = a1;
    *reinterpret_cast<f32x4*>(&s_acc[part][128 + l16 * 4]) = a2;
    *reinterpret_cast<f32x4*>(&s_acc[part][192 + l16 * 4]) = a3;
    if (l16 == 0) s_s[part] = s;
    __syncthreads();

    int c = threadIdx.x;
    float v = 0.f;
    #pragma unroll
    for (int p = 0; p < 16; ++p) v += s_acc[p][c];
    yp[(size_t)b * FDIM + c] = v;
    if (threadIdx.x == 0) {
        float t = 0.f;
        #pragma unroll
        for (int p = 0; p < 16; ++p) t += s_s[p];
        sp[b] = t;
    }
}

// k4 (R7 byte-exact): merge the 2 partials per segment, normalize,
// out = ynorm @ Wn + sum_alpha (x) bn.  2 segments per 256-thread block ->
// 512 blocks (2/CU overlap each other).
__global__ void __launch_bounds__(256) k4_out(const float* __restrict__ yp,
                                              const float* __restrict__ sp,
                                              const float* __restrict__ Wn,
                                              const float* __restrict__ bn,
                                              float* __restrict__ out, int G) {
    int g0 = blockIdx.x * K4_ROWS;
    __shared__ float ys[K4_ROWS][FDIM];
    __shared__ float s_alpha[K4_ROWS];
    int c = threadIdx.x;
    #pragma unroll
    for (int r = 0; r < K4_ROWS; ++r) {
        int g = g0 + r;
        if (g < G) {
            float sg = sp[2 * g] + sp[2 * g + 1];
            float inv = 1.0f / (sg + EPSF);
            ys[r][c] = (yp[(size_t)(2 * g) * FDIM + c] +
                        yp[(size_t)(2 * g + 1) * FDIM + c]) * inv;
            if (c == 0) s_alpha[r] = sg * inv;
        } else {
            ys[r][c] = 0.f;
            if (c == 0) s_alpha[r] = 0.f;
        }
    }
    __syncthreads();
    float acc[K4_ROWS];
    #pragma unroll
    for (int r = 0; r < K4_ROWS; ++r) acc[r] = 0.f;
    #pragma unroll 8
    for (int k = 0; k < FDIM; ++k) {
        float w = Wn[k * FDIM + c];
        #pragma unroll
        for (int r = 0; r < K4_ROWS; ++r) acc[r] += ys[r][k] * w;
    }
    float bv = bn[c];
    #pragma unroll
    for (int r = 0; r < K4_ROWS; ++r) {
        int g = g0 + r;
        if (g < G) out[(size_t)g * FDIM + c] = acc[r] + s_alpha[r] * bv;
    }
}

extern "C" void kernel_launch(void* const* d_in, const int* in_sizes, int n_in,
                              void* d_out, int out_size, void* d_ws, size_t ws_size,
                              hipStream_t stream) {
    const float* x     = (const float*)d_in[0];
    const int*   batch = (const int*)d_in[1];
    const float* Wg    = (const float*)d_in[3];
    const float* Wn    = (const float*)d_in[5];
    const float* bn    = (const float*)d_in[6];
    float* out = (float*)d_out;

    int N = in_sizes[1];
    int G = out_size / FDIM;

    int*   seg_start = (int*)d_ws;                     // G+1 ints
    float* sp = (float*)(seg_start + ((G + 2) & ~1));  // 2G floats
    float* yp = sp + 2 * G;                            // 2G * FDIM floats

    k_ranges<<<(N + 1 + 255) / 256, 256, 0, stream>>>(batch, seg_start, N, G);
    k_fused<<<2 * G, 256, 0, stream>>>(seg_start, x, Wg, yp, sp);
    k4_out<<<(G + K4_ROWS - 1) / K4_ROWS, 256, 0, stream>>>(yp, sp, Wn, bn, out, G);
}